// Round 7
// baseline (31.149 us; speedup 1.0000x reference)
//
#include <hip/hip_runtime.h>
#include <hip/hip_bf16.h>

#define DD 256
#define NROWS 16384

typedef float f32x4 __attribute__((ext_vector_type(4)));
typedef __bf16 bf16x4 __attribute__((ext_vector_type(4)));
typedef __bf16 bf16x8 __attribute__((ext_vector_type(8)));

// Async global->LDS DMA, 16B per lane: HW writes lds_base + lane*16 (dest must
// be wave-uniform); global src is per-lane (enables pre-swizzled sources).
__device__ __forceinline__ void gl2lds16(const void* g, void* l) {
  __builtin_amdgcn_global_load_lds(
      (const __attribute__((address_space(1))) void*)g,
      (__attribute__((address_space(3))) void*)l, 16, 0, 0);
}

// ---------------------------------------------------------------------------
// K1: Wc = Wout @ Wv (bf16), bc = bout + Wout @ bv.
// 64 blocks x 256 thr; block = 4 Wc rows x all 256 cols. Wv streamed in
// 32-row (32KB) chunks via async global_load_lds, double-buffered LDS.
// Wave w owns output row i0+w; lane l owns cols 4l..4l+3 (f32x4 acc).
// LDS reads are stride-1 (conflict-free); wout_s reads are broadcasts.
// ---------------------------------------------------------------------------
__global__ __launch_bounds__(256) void wc_bc_kernel(
    const float* __restrict__ Wqkv, const float* __restrict__ bqkv,
    const float* __restrict__ Wout, const float* __restrict__ bout,
    __bf16* __restrict__ Wc, float* __restrict__ bc) {
  __shared__ float wout_s[4][DD];     // 4 KiB
  __shared__ float wv_s[2][32 * DD];  // 64 KiB double buffer
  const int t = threadIdx.x;
  const int w = t >> 6, l = t & 63;
  const int i0 = blockIdx.x * 4;
  const float* __restrict__ Wv = Wqkv + 2 * DD * DD;
  const float* __restrict__ bv = bqkv + 2 * DD;

  // Stage the 4 Wout rows (coalesced f32x4 each).
  *(f32x4*)&wout_s[w][l * 4] =
      *(const f32x4*)(Wout + (size_t)(i0 + w) * DD + l * 4);

  // Prefetch Wv chunk 0 (rows 0..31, 32KB): 8 async DMA insts per thread-wave.
#pragma unroll
  for (int j = 0; j < 8; ++j)
    gl2lds16((const char*)Wv + (size_t)(j * 4096 + w * 1024 + l * 16),
             (char*)&wv_s[0][0] + j * 4096 + w * 1024);
  __syncthreads();  // drains vmcnt (DMA) + lgkm (ds_write)

  f32x4 acc = {0.f, 0.f, 0.f, 0.f};
  for (int c = 0; c < 8; ++c) {
    if (c < 7) {  // issue next chunk into the other buffer before computing
      const char* src = (const char*)(Wv + (size_t)(c + 1) * 32 * DD);
#pragma unroll
      for (int j = 0; j < 8; ++j)
        gl2lds16(src + (size_t)(j * 4096 + w * 1024 + l * 16),
                 (char*)&wv_s[(c + 1) & 1][0] + j * 4096 + w * 1024);
    }
    const float* wv = &wv_s[c & 1][0];
#pragma unroll
    for (int d = 0; d < 32; ++d) {
      const float s = wout_s[w][c * 32 + d];          // LDS broadcast
      f32x4 vv = *(const f32x4*)(wv + d * DD + l * 4);  // stride-1 b128
      acc += vv * s;
    }
    __syncthreads();  // waves done with buf[c&1]; chunk c+1 landed
  }

  bf16x4 o;
#pragma unroll
  for (int j = 0; j < 4; ++j) o[j] = (__bf16)acc[j];
  *(bf16x4*)(Wc + (size_t)(i0 + w) * DD + l * 4) = o;

  // bc[i0+w] = bout + <Wout row, bv>
  float p = 0.f;
#pragma unroll
  for (int k = 0; k < 4; ++k) p += wout_s[w][l + 64 * k] * bv[l + 64 * k];
#pragma unroll
  for (int off = 32; off > 0; off >>= 1) p += __shfl_down(p, off);
  if (l == 0) bc[i0 + w] = bout[i0 + w] + p;
}

// ---------------------------------------------------------------------------
// K2: out = x + x @ Wc^T + bc.
// Block = 16 rows x 64 out-cols; grid = 1024 rowtiles x 4 colgroups = 4096.
// Wc slice (64 rows x 256 k bf16 = 32KB) staged via async global_load_lds
// with PRE-SWIZZLED global source (linear dest + inverse-swz src + swz read).
// x tile (16 x 256) reg-staged to bf16 LDS, same XOR swizzle.
// Wave w: out-cols cbase+16w..+15 (A = Wc rows), B = 16 x-rows; 8 MFMA.
// LDS = 40KB -> 4 blocks/CU resident, 16 blocks/CU queued.
// ---------------------------------------------------------------------------
__global__ __launch_bounds__(256, 4) void knn_attn_main(
    const float* __restrict__ x, const __bf16* __restrict__ Wc,
    const float* __restrict__ bc, float* __restrict__ out) {
  __shared__ __bf16 wc_s[64 * DD];  // 32 KiB, swizzled rows of 512B
  __shared__ __bf16 xs_s[16 * DD];  // 8 KiB, swizzled rows of 512B
  const int t = threadIdx.x;
  const int w = t >> 6, l = t & 63;
  const int R0 = (blockIdx.x >> 2) * 16;
  const int cbase = (blockIdx.x & 3) * 64;

  // ---- Wc slice stage: lds[row][i] = Wc[cbase+row][i ^ sw(row)]
  {
    const char* wsrc = (const char*)(Wc + (size_t)cbase * DD);
#pragma unroll
    for (int j = 0; j < 8; ++j) {
      const int L = j * 4096 + w * 1024 + l * 16;  // linear dest byte offset
      const int row = L >> 9;
      const int srow = (L & 511) ^ ((row & 7) << 4);  // inverse swizzle (XOR)
      gl2lds16(wsrc + (size_t)row * 512 + srow,
               (char*)wc_s + (j * 4096 + w * 1024));  // wave-uniform dest
    }
  }

  // ---- x tile stage: fp32 -> bf16, swizzled ds writes (reg-staged).
  {
    const int xr = t >> 4;   // row 0..15
    const int seg = t & 15;  // 16 fp32 per thread
    const float* src = x + (size_t)(R0 + xr) * DD + seg * 16;
    f32x4 v0 = *(const f32x4*)(src + 0);
    f32x4 v1 = *(const f32x4*)(src + 4);
    f32x4 v2 = *(const f32x4*)(src + 8);
    f32x4 v3 = *(const f32x4*)(src + 12);
    bf16x8 b0, b1;
#pragma unroll
    for (int j = 0; j < 4; ++j) {
      b0[j] = (__bf16)v0[j];
      b0[4 + j] = (__bf16)v1[j];
      b1[j] = (__bf16)v2[j];
      b1[4 + j] = (__bf16)v3[j];
    }
    const int base = xr * 512 + seg * 32;
    const int sw = (xr & 7) << 4;
    *(bf16x8*)((char*)xs_s + ((base + 0) ^ sw)) = b0;
    *(bf16x8*)((char*)xs_s + ((base + 16) ^ sw)) = b1;
  }
  __syncthreads();  // drains DMA (vmcnt) + ds writes (lgkm)

  // ---- MFMA: A = wc_s rows (out-cols), B = xs_s rows (x-rows).
  const int colL = w * 16 + (l & 15);  // wc_s row = out-col local
  const int g = l >> 4;
  const int xrow = l & 15;
  const int csw = (colL & 7) << 4;
  const int xsw = (xrow & 7) << 4;
  f32x4 acc = {0.f, 0.f, 0.f, 0.f};
#pragma unroll
  for (int ks = 0; ks < 8; ++ks) {
    const int kb = ks * 64 + g * 16;  // byte offset of k-slice within row
    bf16x8 af = *(const bf16x8*)((const char*)wc_s + ((colL * 512 + kb) ^ csw));
    bf16x8 bf = *(const bf16x8*)((const char*)xs_s + ((xrow * 512 + kb) ^ xsw));
    acc = __builtin_amdgcn_mfma_f32_16x16x32_bf16(af, bf, acc, 0, 0, 0);
  }

  // ---- Epilogue: D col(l&15)=x-row, D row(g*4+reg)=out-col offset.
  const int ocol = cbase + w * 16 + g * 4;
  const size_t idx = (size_t)(R0 + xrow) * DD + ocol;
  f32x4 xres = *(const f32x4*)(x + idx);   // exact fp32 residual (L2/L3 hot)
  f32x4 bias = *(const f32x4*)(bc + ocol); // includes bout
  *(f32x4*)(out + idx) = acc + xres + bias;
}

extern "C" void kernel_launch(void* const* d_in, const int* in_sizes, int n_in,
                              void* d_out, int out_size, void* d_ws, size_t ws_size,
                              hipStream_t stream) {
  const float* x = (const float*)d_in[0];
  const float* Wqkv = (const float*)d_in[1];
  const float* bqkv = (const float*)d_in[2];
  const float* Wout = (const float*)d_in[3];
  const float* bout = (const float*)d_in[4];
  float* out = (float*)d_out;

  __bf16* Wc = (__bf16*)d_ws;                                   // 128 KiB
  float* bc = (float*)((char*)d_ws + DD * DD * sizeof(__bf16)); // +1 KiB

  wc_bc_kernel<<<64, 256, 0, stream>>>(Wqkv, bqkv, Wout, bout, Wc, bc);
  knn_attn_main<<<(NROWS / 16) * 4, 256, 0, stream>>>(x, Wc, bc, out);
}